// Round 8
// baseline (216.081 us; speedup 1.0000x reference)
//
#include <hip/hip_runtime.h>
#include <hip/hip_bf16.h>
#include <math.h>

typedef __bf16 bf16;
typedef __bf16 bf16x8 __attribute__((ext_vector_type(8)));
typedef __bf16 bf16x4 __attribute__((ext_vector_type(4)));
typedef float f32x4 __attribute__((ext_vector_type(4)));

#define MFMA16(a, b, c) __builtin_amdgcn_mfma_f32_16x16x32_bf16((a), (b), (c), 0, 0, 0)

__device__ __forceinline__ void gload_lds16(const void* g, void* l) {
  __builtin_amdgcn_global_load_lds((__attribute__((address_space(1))) void*)(g),
                                   (__attribute__((address_space(3))) void*)(l),
                                   16, 0, 0);
}

// ---------------- fp32 -> bf16 conversion ----------------
__global__ __launch_bounds__(256) void f2bf_kernel(const float* __restrict__ in,
                                                   bf16* __restrict__ out, int n4) {
  int i = blockIdx.x * 256 + threadIdx.x;
  if (i >= n4) return;
  float4 v = ((const float4*)in)[i];
  bf16x4 o;
  o[0] = (bf16)v.x; o[1] = (bf16)v.y; o[2] = (bf16)v.z; o[3] = (bf16)v.w;
  *(bf16x4*)(out + (size_t)i * 4) = o;
}

// ---------------- ns = cond @ norm_w.T + 1 ----------------
__global__ __launch_bounds__(256) void ns_kernel(const float* __restrict__ cond,
                                                 const float* __restrict__ norm_w,
                                                 float* __restrict__ nsp1) {
  int tid = blockIdx.x * 256 + threadIdx.x;  // 8192 = 8 * 1024
  int b = tid >> 10, c = tid & 1023;
  const float4* wv = (const float4*)(norm_w + (size_t)c * 768);
  const float4* cv = (const float4*)(cond + (size_t)b * 768);
  float acc = 0.f;
#pragma unroll 8
  for (int i = 0; i < 192; ++i) {
    float4 w4 = wv[i], c4 = cv[i];
    acc += w4.x * c4.x + w4.y * c4.y + w4.z * c4.z + w4.w * c4.w;
  }
  nsp1[tid] = acc + 1.0f;
}

// ---------------- RMSNorm * (ns+1) -> bf16 ----------------
__global__ __launch_bounds__(256) void rmsnorm_kernel(const float* __restrict__ x,
                                                      const float* __restrict__ nsp1,
                                                      bf16* __restrict__ xn) {
  int lane = threadIdx.x & 63, w = threadIdx.x >> 6;
  int m = blockIdx.x * 4 + w;  // token id, 8192 total
  int b = m >> 10;
  const float* xp = x + (size_t)m * 1024 + lane * 16;
  float v[16];
  float ss = 0.f;
#pragma unroll
  for (int i = 0; i < 4; ++i) {
    float4 t4 = ((const float4*)xp)[i];
    v[4 * i + 0] = t4.x; v[4 * i + 1] = t4.y; v[4 * i + 2] = t4.z; v[4 * i + 3] = t4.w;
    ss += t4.x * t4.x + t4.y * t4.y + t4.z * t4.z + t4.w * t4.w;
  }
#pragma unroll
  for (int off = 32; off >= 1; off >>= 1) ss += __shfl_xor(ss, off);
  float r = rsqrtf(ss * (1.0f / 1024.0f) + 1e-6f);
  const float* np = nsp1 + (size_t)b * 1024 + lane * 16;
  bf16x8 o0, o1;
#pragma unroll
  for (int j = 0; j < 8; ++j) o0[j] = (bf16)(v[j] * np[j] * r);
#pragma unroll
  for (int j = 0; j < 8; ++j) o1[j] = (bf16)(v[8 + j] * np[8 + j] * r);
  bf16* op = xn + (size_t)m * 1024 + lane * 16;
  *(bf16x8*)op = o0;
  *(bf16x8*)(op + 8) = o1;
}

// ---------------- 256x256-tile GEMM, 8 waves (128x64 wave tile), ring-2 ----------------
// C[m,n] = sum_k A[m,k]*B[n,k], K=1024.
// MODE 0: fused epilogue — q/k: L2-norm * sqrt(scale) (+log2e for q) + RoPE, scatter
//         to (b,h,s,d); v: scatter transposed (b,h,d,s).
// MODE 1: out = C + skip (fp32).
template <int MODE>
__global__ __launch_bounds__(512, 2) void gemm256c(const bf16* __restrict__ A,
                                                   const bf16* __restrict__ B, int nbn,
                                                   bf16* __restrict__ qout, bf16* __restrict__ kout,
                                                   bf16* __restrict__ vtout, float* __restrict__ fout,
                                                   const float* __restrict__ skip,
                                                   const float* __restrict__ pos,
                                                   const float* __restrict__ scale) {
  constexpr int K = 1024;
  // 2 slots x (A 8192 + B 8192 elems) = 64 KB
  __shared__ __align__(16) bf16 sm[32768];
  const int t = threadIdx.x;
  const int cpx = gridDim.x >> 3;  // grid % 8 == 0
  const int bid = blockIdx.x;
  const int virt = (bid & 7) * cpx + (bid >> 3);
  const int bn = virt % nbn, bm = virt / nbn;
  const int m0 = bm * 256, n0 = bn * 256;
  const int lane = t & 63, wid = t >> 6;
  const int wr = wid >> 2, wc = wid & 3;  // 2x4 wave grid, wave tile 128x64
  const int r16 = lane & 15, hi = lane >> 4;

  // staging (inverse-swizzled global source, linear LDS dest); each pass = 128 rows x 32 cols
  const int tq = t >> 3, c8 = t & 7, cp = c8 ^ (tq & 7);
  const size_t gA = (size_t)(m0 + tq * 2 + (cp >> 2)) * K + (cp & 3) * 8;
  const size_t gB = (size_t)(n0 + tq * 2 + (cp >> 2)) * K + (cp & 3) * 8;
  const size_t gj = (size_t)128 * K;
  const int ldst = t * 8;

  // fragment read offsets (2 k32-rows packed per 128B LDS row, XOR-swizzled chunks)
  const int chunk = ((r16 & 1) * 4 + hi) ^ (r16 >> 1);
  int aoff[8], boff[4];
#pragma unroll
  for (int fr = 0; fr < 8; ++fr) aoff[fr] = (wr * 64 + fr * 8 + (r16 >> 1)) * 64 + chunk * 8;
#pragma unroll
  for (int fc = 0; fc < 4; ++fc)
    boff[fc] = (wc * 32 + fc * 8 + (r16 >> 1)) * 64 + chunk * 8 + 8192;

  f32x4 acc[8][4] = {};
  constexpr int NS = K >> 5;  // 32

#define STG(tile, slot)                                                  \
  {                                                                      \
    const bf16* as_ = A + gA + (size_t)(tile) * 32;                      \
    const bf16* bs_ = B + gB + (size_t)(tile) * 32;                      \
    gload_lds16(as_, &sm[(slot) * 16384 + ldst]);                        \
    gload_lds16(as_ + gj, &sm[(slot) * 16384 + 4096 + ldst]);            \
    gload_lds16(bs_, &sm[(slot) * 16384 + 8192 + ldst]);                 \
    gload_lds16(bs_ + gj, &sm[(slot) * 16384 + 12288 + ldst]);           \
  }

  STG(0, 0);
  STG(1, 1);

  for (int s = 0; s < NS; ++s) {
    if (s < NS - 1) {
      asm volatile("s_waitcnt vmcnt(4)" ::: "memory");
    } else {
      asm volatile("s_waitcnt vmcnt(0)" ::: "memory");
    }
    __builtin_amdgcn_s_barrier();
    __builtin_amdgcn_sched_barrier(0);
    bf16x8 af[8], bfr[4];
    const bf16* base = &sm[(s & 1) * 16384];
#pragma unroll
    for (int fr = 0; fr < 8; ++fr) af[fr] = *(const bf16x8*)&base[aoff[fr]];
#pragma unroll
    for (int fc = 0; fc < 4; ++fc) bfr[fc] = *(const bf16x8*)&base[boff[fc]];
    asm volatile("s_waitcnt lgkmcnt(0)" ::: "memory");
    __builtin_amdgcn_sched_barrier(0);
    __builtin_amdgcn_s_barrier();
    __builtin_amdgcn_sched_barrier(0);
    if (s + 2 < NS) STG(s + 2, s & 1);
    __builtin_amdgcn_s_setprio(1);
#pragma unroll
    for (int fc = 0; fc < 4; ++fc)
#pragma unroll
      for (int fr = 0; fr < 8; ++fr) acc[fr][fc] = MFMA16(af[fr], bfr[fc], acc[fr][fc]);
    __builtin_amdgcn_s_setprio(0);
  }
#undef STG

  if constexpr (MODE == 0) {
    const int p = n0 >> 10;  // uniform per block: 0=q, 1=k, 2=v
    if (p == 2) {
#pragma unroll
      for (int fr = 0; fr < 8; ++fr) {
        int mrow = m0 + wr * 128 + fr * 16 + hi * 4;
        int b = mrow >> 10, s0 = mrow & 1023;
#pragma unroll
        for (int fc = 0; fc < 4; ++fc) {
          int n = n0 + wc * 64 + fc * 16 + r16;
          int d = n & 63, hh = (n >> 6) & 15;
          bf16x4 pk;
          pk[0] = (bf16)acc[fr][fc][0]; pk[1] = (bf16)acc[fr][fc][1];
          pk[2] = (bf16)acc[fr][fc][2]; pk[3] = (bf16)acc[fr][fc][3];
          *(bf16x4*)&vtout[(((size_t)(b * 16 + hh) * 64 + d) << 10) + s0] = pk;
        }
      }
    } else {
      // fused q/k norm + RoPE. Wave covers one head's full 64 dims: d = fc*16 + r16.
      const int hh = ((n0 + wc * 64) >> 6) & 15;
      const float LOG2E = 1.4426950408889634f;
      const float sqv = sqrtf(scale[hh]) * (p == 0 ? LOG2E : 1.0f);
      const float f = __expf(1.14472988584940017f +
                             0.0179897502011134460f * (float)((r16 & 7) * 16 + hh));
      const bool is_h = (r16 < 8);
      bf16* dst = (p == 0) ? qout : kout;
#pragma unroll
      for (int fr = 0; fr < 8; ++fr) {
        int mrow = m0 + wr * 128 + fr * 16 + hi * 4;
        int b = mrow >> 10, s0 = mrow & 1023;
        float rr[4];
#pragma unroll
        for (int r = 0; r < 4; ++r) {
          float ss = acc[fr][0][r] * acc[fr][0][r] + acc[fr][1][r] * acc[fr][1][r] +
                     acc[fr][2][r] * acc[fr][2][r] + acc[fr][3][r] * acc[fr][3][r];
          ss += __shfl_xor(ss, 1);
          ss += __shfl_xor(ss, 2);
          ss += __shfl_xor(ss, 4);
          ss += __shfl_xor(ss, 8);
          rr[r] = sqv * rsqrtf(ss + 1e-6f);
        }
#pragma unroll
        for (int r = 0; r < 4; ++r) {
          float2 pp = *(const float2*)&pos[(((size_t)b << 10) + s0 + r) * 2];
          float th = (is_h ? pp.x : pp.y) * f;
          float sv, cv;
          __sincosf(th, &sv, &cv);
          float x1 = acc[fr][0][r] * rr[r];
          float x2 = acc[fr][1][r] * rr[r];
          size_t rowb = (((size_t)(b * 16 + hh) << 10) + s0 + r) * 64;
          dst[rowb + r16]      = (bf16)(x1 * cv - x2 * sv);
          dst[rowb + 16 + r16] = (bf16)(x2 * cv + x1 * sv);
          dst[rowb + 32 + r16] = (bf16)(acc[fr][2][r] * rr[r]);
          dst[rowb + 48 + r16] = (bf16)(acc[fr][3][r] * rr[r]);
        }
      }
    }
  } else {
#pragma unroll
    for (int fr = 0; fr < 8; ++fr) {
      int mrow = m0 + wr * 128 + fr * 16 + hi * 4;
#pragma unroll
      for (int fc = 0; fc < 4; ++fc) {
        int n = n0 + wc * 64 + fc * 16 + r16;
#pragma unroll
        for (int r = 0; r < 4; ++r) {
          size_t off = (size_t)(mrow + r) * 1024 + n;
          fout[off] = acc[fr][fc][r] + skip[off];
        }
      }
    }
  }
}

// ---------------- flash attention v5: 8 waves, QBLK=128 ----------------
// K+V LDS dbuf (shared by 8 waves), swapped QK^T, shift-free softmax (bounded scores),
// l via ones-column MFMA.
__global__ __launch_bounds__(512, 4) void attn_kernel(const bf16* __restrict__ q,
                                                      const bf16* __restrict__ k,
                                                      const bf16* __restrict__ vt,
                                                      bf16* __restrict__ o) {
  int bid = blockIdx.x;  // 1024 blocks
  int virt = (bid & 7) * 128 + (bid >> 3);
  const int bh = virt >> 3;     // (b*16+h)
  const int qt = virt & 7;      // q-tile of 128
  const int b = bh >> 4, h = bh & 15;
  const int t = threadIdx.x, lane = t & 63, w = t >> 6;
  const int r16 = lane & 15, hi = lane >> 4;
  const int swp = r16 & 7;

  __shared__ bf16 lK[2][4096];
  __shared__ bf16 lV[2][4096];
  __shared__ bf16 lP[8][1024];
  bf16* myp = lP[w];

  const bf16* kp = k + (size_t)bh * 65536;
  const bf16* vp = vt + (size_t)bh * 65536;  // (d, s) layout

  const bf16* qp = q + ((size_t)bh * 1024 + qt * 128 + w * 16) * 64;
  bf16x8 aq0 = *(const bf16x8*)&qp[r16 * 64 + hi * 8];
  bf16x8 aq1 = *(const bf16x8*)&qp[r16 * 64 + 32 + hi * 8];

  bf16x8 ones;
#pragma unroll
  for (int i = 0; i < 8; ++i) ones[i] = (bf16)1.0f;

  // staging: 512 threads cover a full 64x64 tile in one pass (1 load K, 1 load V)
  const int srow0 = t >> 3, sc0 = t & 7;
  const int se = ((sc0 ^ (srow0 & 7)) << 3);

  f32x4 oacc[4] = {};
  f32x4 lacc = {};

  // prologue: stage K+V tile 0 (inverse-swizzled global source, linear LDS dest)
  gload_lds16(kp + (size_t)srow0 * 64 + se, &lK[0][t * 8]);
  gload_lds16(vp + (size_t)srow0 * 1024 + se, &lV[0][t * 8]);
  __syncthreads();

  int cur = 0;
  for (int kt = 0; kt < 16; ++kt) {
    if (kt < 15) {
      gload_lds16(kp + (kt + 1) * 4096 + (size_t)srow0 * 64 + se, &lK[cur ^ 1][t * 8]);
      gload_lds16(vp + (kt + 1) * 64 + (size_t)srow0 * 1024 + se, &lV[cur ^ 1][t * 8]);
    }
    // ---- swapped QK^T: sT[c][r] = S[q=r16][k = c*16 + hi*4 + r] (log2-scaled) ----
    f32x4 sT[4] = {};
    __builtin_amdgcn_s_setprio(1);
#pragma unroll
    for (int c = 0; c < 4; ++c) {
      int row = c * 16 + r16, sw = row & 7;
      bf16x8 bk0 = *(const bf16x8*)&lK[cur][row * 64 + ((hi ^ sw) << 3)];
      bf16x8 bk1 = *(const bf16x8*)&lK[cur][row * 64 + (((hi + 4) ^ sw) << 3)];
      sT[c] = MFMA16(bk0, aq0, sT[c]);
      sT[c] = MFMA16(bk1, aq1, sT[c]);
    }
    __builtin_amdgcn_s_setprio(0);
    // ---- shift-free softmax: p = exp2(sT)  (bounded scores, no max/rescale) ----
    bf16x4 pb[4];
#pragma unroll
    for (int c = 0; c < 4; ++c) {
#pragma unroll
      for (int r = 0; r < 4; ++r) pb[c][r] = (bf16)exp2f(sT[c][r]);
    }
    // P[q=r16][k=c*16+hi*4 .. +3] as one b64 store, same XOR swizzle as reads
#pragma unroll
    for (int c = 0; c < 4; ++c) {
      int eoff = r16 * 64 + (((c * 32 + hi * 8) ^ (swp << 4)) >> 1);
      *(bf16x4*)&myp[eoff] = pb[c];
    }
    // ---- PV: P (swizzled LDS) x V^T (swizzled LDS); ones-column gives row sums ----
    {
      bf16x8 pa0 = *(const bf16x8*)&myp[r16 * 64 + ((hi ^ swp) << 3)];
      bf16x8 pa1 = *(const bf16x8*)&myp[r16 * 64 + (((hi + 4) ^ swp) << 3)];
      __builtin_amdgcn_s_setprio(1);
#pragma unroll
      for (int c = 0; c < 4; ++c) {
        int row = c * 16 + r16, sw = row & 7;
        bf16x8 bv0 = *(const bf16x8*)&lV[cur][row * 64 + ((hi ^ sw) << 3)];
        bf16x8 bv1 = *(const bf16x8*)&lV[cur][row * 64 + (((hi + 4) ^ sw) << 3)];
        oacc[c] = MFMA16(pa0, bv0, oacc[c]);
        oacc[c] = MFMA16(pa1, bv1, oacc[c]);
      }
      lacc = MFMA16(pa0, ones, lacc);
      lacc = MFMA16(pa1, ones, lacc);
      __builtin_amdgcn_s_setprio(0);
    }
    __syncthreads();
    cur ^= 1;
  }
  // epilogue: lacc rows are q = hi*4 + r, matching oacc — no shuffles needed
  f32x4 inv;
#pragma unroll
  for (int r = 0; r < 4; ++r) inv[r] = 1.f / lacc[r];
#pragma unroll
  for (int c = 0; c < 4; ++c) {
#pragma unroll
    for (int r = 0; r < 4; ++r) {
      int srow = qt * 128 + w * 16 + hi * 4 + r;
      o[((size_t)b * 1024 + srow) * 1024 + h * 64 + c * 16 + r16] =
          (bf16)(oacc[c][r] * inv[r]);
    }
  }
}

extern "C" void kernel_launch(void* const* d_in, const int* in_sizes, int n_in,
                              void* d_out, int out_size, void* d_ws, size_t ws_size,
                              hipStream_t stream) {
  const float* x      = (const float*)d_in[0];  // (8,32,32,1024)
  const float* pos    = (const float*)d_in[1];  // (8,32,32,2)
  const float* cond   = (const float*)d_in[2];  // (8,768)
  const float* norm_w = (const float*)d_in[3];  // (1024,768)
  const float* qkv_w  = (const float*)d_in[4];  // (3072,1024)
  const float* out_w  = (const float*)d_in[5];  // (1024,1024)
  const float* scale  = (const float*)d_in[6];  // (16,)
  float* out = (float*)d_out;

  char* ws = (char*)d_ws;
  bf16* xn        = (bf16*)(ws + 0);           // 16.8 MB (reused as o_attn)
  bf16* qkv_w_bf  = (bf16*)(ws + 16777216);    // 6.3 MB
  bf16* out_w_bf  = (bf16*)(ws + 23068672);    // 2.1 MB
  float* nsp1     = (float*)(ws + 25165824);   // 32 KB
  bf16* qraw      = (bf16*)(ws + 25198592);    // 16.8 MB
  bf16* kraw      = (bf16*)(ws + 41975808);    // 16.8 MB
  bf16* vt        = (bf16*)(ws + 58753024);    // 16.8 MB
  bf16* o_attn    = xn;

  f2bf_kernel<<<3072, 256, 0, stream>>>(qkv_w, qkv_w_bf, 786432);
  f2bf_kernel<<<1024, 256, 0, stream>>>(out_w, out_w_bf, 262144);
  ns_kernel<<<32, 256, 0, stream>>>(cond, norm_w, nsp1);
  rmsnorm_kernel<<<2048, 256, 0, stream>>>(x, nsp1, xn);
  gemm256c<0><<<384, 512, 0, stream>>>(xn, qkv_w_bf, 12, qraw, kraw, vt, nullptr, nullptr,
                                       pos, scale);
  attn_kernel<<<1024, 512, 0, stream>>>(qraw, kraw, vt, o_attn);
  gemm256c<1><<<128, 512, 0, stream>>>(o_attn, out_w_bf, 4, nullptr, nullptr, nullptr, out, x,
                                       nullptr, nullptr);
}

// Round 9
// 194.155 us; speedup vs baseline: 1.1129x; 1.1129x over previous
//
#include <hip/hip_runtime.h>
#include <hip/hip_bf16.h>
#include <math.h>

typedef __bf16 bf16;
typedef __bf16 bf16x8 __attribute__((ext_vector_type(8)));
typedef __bf16 bf16x4 __attribute__((ext_vector_type(4)));
typedef float f32x4 __attribute__((ext_vector_type(4)));

#define MFMA16(a, b, c) __builtin_amdgcn_mfma_f32_16x16x32_bf16((a), (b), (c), 0, 0, 0)

__device__ __forceinline__ void gload_lds16(const void* g, void* l) {
  __builtin_amdgcn_global_load_lds((__attribute__((address_space(1))) void*)(g),
                                   (__attribute__((address_space(3))) void*)(l),
                                   16, 0, 0);
}

// ---------------- fp32 -> bf16 conversion ----------------
__global__ __launch_bounds__(256) void f2bf_kernel(const float* __restrict__ in,
                                                   bf16* __restrict__ out, int n4) {
  int i = blockIdx.x * 256 + threadIdx.x;
  if (i >= n4) return;
  float4 v = ((const float4*)in)[i];
  bf16x4 o;
  o[0] = (bf16)v.x; o[1] = (bf16)v.y; o[2] = (bf16)v.z; o[3] = (bf16)v.w;
  *(bf16x4*)(out + (size_t)i * 4) = o;
}

// ---------------- ns = cond @ norm_w.T + 1 ----------------
__global__ __launch_bounds__(256) void ns_kernel(const float* __restrict__ cond,
                                                 const float* __restrict__ norm_w,
                                                 float* __restrict__ nsp1) {
  int tid = blockIdx.x * 256 + threadIdx.x;  // 8192 = 8 * 1024
  int b = tid >> 10, c = tid & 1023;
  const float4* wv = (const float4*)(norm_w + (size_t)c * 768);
  const float4* cv = (const float4*)(cond + (size_t)b * 768);
  float acc = 0.f;
#pragma unroll 8
  for (int i = 0; i < 192; ++i) {
    float4 w4 = wv[i], c4 = cv[i];
    acc += w4.x * c4.x + w4.y * c4.y + w4.z * c4.z + w4.w * c4.w;
  }
  nsp1[tid] = acc + 1.0f;
}

// ---------------- RMSNorm * (ns+1) -> bf16 ----------------
__global__ __launch_bounds__(256) void rmsnorm_kernel(const float* __restrict__ x,
                                                      const float* __restrict__ nsp1,
                                                      bf16* __restrict__ xn) {
  int lane = threadIdx.x & 63, w = threadIdx.x >> 6;
  int m = blockIdx.x * 4 + w;  // token id, 8192 total
  int b = m >> 10;
  const float* xp = x + (size_t)m * 1024 + lane * 16;
  float v[16];
  float ss = 0.f;
#pragma unroll
  for (int i = 0; i < 4; ++i) {
    float4 t4 = ((const float4*)xp)[i];
    v[4 * i + 0] = t4.x; v[4 * i + 1] = t4.y; v[4 * i + 2] = t4.z; v[4 * i + 3] = t4.w;
    ss += t4.x * t4.x + t4.y * t4.y + t4.z * t4.z + t4.w * t4.w;
  }
#pragma unroll
  for (int off = 32; off >= 1; off >>= 1) ss += __shfl_xor(ss, off);
  float r = rsqrtf(ss * (1.0f / 1024.0f) + 1e-6f);
  const float* np = nsp1 + (size_t)b * 1024 + lane * 16;
  bf16x8 o0, o1;
#pragma unroll
  for (int j = 0; j < 8; ++j) o0[j] = (bf16)(v[j] * np[j] * r);
#pragma unroll
  for (int j = 0; j < 8; ++j) o1[j] = (bf16)(v[8 + j] * np[8 + j] * r);
  bf16* op = xn + (size_t)m * 1024 + lane * 16;
  *(bf16x8*)op = o0;
  *(bf16x8*)(op + 8) = o1;
}

// ---------------- 256x128-tile GEMM, 8 waves, ring-2, counted vmcnt ----------------
// C[m,n] = sum_k A[m,k]*B[n,k], K=1024.  (proven 77us config, round 7)
// MODE 0: fused epilogue — q/k: L2-norm * sqrt(scale) (+log2e for q) + RoPE, scatter
//         to (b,h,s,d); v: scatter transposed (b,h,d,s).
// MODE 1: out = C + skip (fp32).
template <int MODE>
__global__ __launch_bounds__(512, 2) void gemm256b(const bf16* __restrict__ A,
                                                   const bf16* __restrict__ B, int nbn,
                                                   bf16* __restrict__ qout, bf16* __restrict__ kout,
                                                   bf16* __restrict__ vtout, float* __restrict__ fout,
                                                   const float* __restrict__ skip,
                                                   const float* __restrict__ pos,
                                                   const float* __restrict__ scale) {
  constexpr int K = 1024;
  // 2 slots x (A 8192 + B 4096 elems) = 48 KB -> 3 blocks/CU
  __shared__ __align__(16) bf16 sm[24576];
  const int t = threadIdx.x;
  const int cpx = gridDim.x >> 3;  // grid % 8 == 0
  const int bid = blockIdx.x;
  const int virt = (bid & 7) * cpx + (bid >> 3);
  const int bn = virt % nbn, bm = virt / nbn;
  const int m0 = bm * 256, n0 = bn * 128;
  const int lane = t & 63, wid = t >> 6;
  const int wr = wid >> 1, wc = wid & 1;  // 4x2 wave grid, wave tile 64x64
  const int r16 = lane & 15, hi = lane >> 4;

  // staging (inverse-swizzled global source, linear LDS dest)
  const int tq = t >> 3, c8 = t & 7, cp = c8 ^ (tq & 7);
  const size_t gA = (size_t)(m0 + tq * 2 + (cp >> 2)) * K + (cp & 3) * 8;
  const size_t gB = (size_t)(n0 + tq * 2 + (cp >> 2)) * K + (cp & 3) * 8;
  const size_t gj = (size_t)128 * K;
  const int ldst = t * 8;

  // fragment read offsets (2 k32-rows packed per 128B LDS row, XOR-swizzled chunks)
  const int chunk = ((r16 & 1) * 4 + hi) ^ (r16 >> 1);
  int aoff[4], boff[4];
#pragma unroll
  for (int fr = 0; fr < 4; ++fr) aoff[fr] = (wr * 32 + fr * 8 + (r16 >> 1)) * 64 + chunk * 8;
#pragma unroll
  for (int fc = 0; fc < 4; ++fc)
    boff[fc] = (wc * 32 + fc * 8 + (r16 >> 1)) * 64 + chunk * 8 + 8192;

  f32x4 acc[4][4] = {};
  constexpr int NS = K >> 5;  // 32

#define STG(tile, slot)                                              \
  {                                                                  \
    const bf16* as_ = A + gA + (size_t)(tile) * 32;                  \
    const bf16* bs_ = B + gB + (size_t)(tile) * 32;                  \
    gload_lds16(as_, &sm[(slot) * 12288 + ldst]);                    \
    gload_lds16(as_ + gj, &sm[(slot) * 12288 + 4096 + ldst]);        \
    gload_lds16(bs_, &sm[(slot) * 12288 + 8192 + ldst]);             \
  }

  STG(0, 0);
  STG(1, 1);

  for (int s = 0; s < NS; ++s) {
    if (s < NS - 1) {
      asm volatile("s_waitcnt vmcnt(3)" ::: "memory");
    } else {
      asm volatile("s_waitcnt vmcnt(0)" ::: "memory");
    }
    __builtin_amdgcn_s_barrier();
    __builtin_amdgcn_sched_barrier(0);
    bf16x8 af[4], bfr[4];
    const bf16* base = &sm[(s & 1) * 12288];
#pragma unroll
    for (int fr = 0; fr < 4; ++fr) af[fr] = *(const bf16x8*)&base[aoff[fr]];
#pragma unroll
    for (int fc = 0; fc < 4; ++fc) bfr[fc] = *(const bf16x8*)&base[boff[fc]];
    asm volatile("s_waitcnt lgkmcnt(0)" ::: "memory");
    __builtin_amdgcn_sched_barrier(0);
    __builtin_amdgcn_s_barrier();
    __builtin_amdgcn_sched_barrier(0);
    if (s + 2 < NS) STG(s + 2, s & 1);
    __builtin_amdgcn_s_setprio(1);
#pragma unroll
    for (int fc = 0; fc < 4; ++fc)
#pragma unroll
      for (int fr = 0; fr < 4; ++fr) acc[fr][fc] = MFMA16(af[fr], bfr[fc], acc[fr][fc]);
    __builtin_amdgcn_s_setprio(0);
  }
#undef STG

  if constexpr (MODE == 0) {
    const int p = n0 >> 10;  // uniform per block: 0=q, 1=k, 2=v
    if (p == 2) {
#pragma unroll
      for (int fr = 0; fr < 4; ++fr) {
        int mrow = m0 + wr * 64 + fr * 16 + hi * 4;
        int b = mrow >> 10, s0 = mrow & 1023;
#pragma unroll
        for (int fc = 0; fc < 4; ++fc) {
          int n = n0 + wc * 64 + fc * 16 + r16;
          int d = n & 63, hh = (n >> 6) & 15;
          bf16x4 pk;
          pk[0] = (bf16)acc[fr][fc][0]; pk[1] = (bf16)acc[fr][fc][1];
          pk[2] = (bf16)acc[fr][fc][2]; pk[3] = (bf16)acc[fr][fc][3];
          *(bf16x4*)&vtout[(((size_t)(b * 16 + hh) * 64 + d) << 10) + s0] = pk;
        }
      }
    } else {
      // fused q/k norm + RoPE. Wave covers one head's full 64 dims: d = fc*16 + r16.
      const int hh = ((n0 + wc * 64) >> 6) & 15;
      const float LOG2E = 1.4426950408889634f;
      const float sqv = sqrtf(scale[hh]) * (p == 0 ? LOG2E : 1.0f);
      const float f = __expf(1.14472988584940017f +
                             0.0179897502011134460f * (float)((r16 & 7) * 16 + hh));
      const bool is_h = (r16 < 8);
      bf16* dst = (p == 0) ? qout : kout;
#pragma unroll
      for (int fr = 0; fr < 4; ++fr) {
        int mrow = m0 + wr * 64 + fr * 16 + hi * 4;
        int b = mrow >> 10, s0 = mrow & 1023;
        float rr[4];
#pragma unroll
        for (int r = 0; r < 4; ++r) {
          float ss = acc[fr][0][r] * acc[fr][0][r] + acc[fr][1][r] * acc[fr][1][r] +
                     acc[fr][2][r] * acc[fr][2][r] + acc[fr][3][r] * acc[fr][3][r];
          ss += __shfl_xor(ss, 1);
          ss += __shfl_xor(ss, 2);
          ss += __shfl_xor(ss, 4);
          ss += __shfl_xor(ss, 8);
          rr[r] = sqv * rsqrtf(ss + 1e-6f);
        }
#pragma unroll
        for (int r = 0; r < 4; ++r) {
          float2 pp = *(const float2*)&pos[(((size_t)b << 10) + s0 + r) * 2];
          float th = (is_h ? pp.x : pp.y) * f;
          float sv, cv;
          __sincosf(th, &sv, &cv);
          float x1 = acc[fr][0][r] * rr[r];
          float x2 = acc[fr][1][r] * rr[r];
          size_t rowb = (((size_t)(b * 16 + hh) << 10) + s0 + r) * 64;
          dst[rowb + r16]      = (bf16)(x1 * cv - x2 * sv);
          dst[rowb + 16 + r16] = (bf16)(x2 * cv + x1 * sv);
          dst[rowb + 32 + r16] = (bf16)(acc[fr][2][r] * rr[r]);
          dst[rowb + 48 + r16] = (bf16)(acc[fr][3][r] * rr[r]);
        }
      }
    }
  } else {
#pragma unroll
    for (int fr = 0; fr < 4; ++fr) {
      int mrow = m0 + wr * 64 + fr * 16 + hi * 4;
#pragma unroll
      for (int fc = 0; fc < 4; ++fc) {
        int n = n0 + wc * 64 + fc * 16 + r16;
#pragma unroll
        for (int r = 0; r < 4; ++r) {
          size_t off = (size_t)(mrow + r) * 1024 + n;
          fout[off] = acc[fr][fc][r] + skip[off];
        }
      }
    }
  }
}

// ---------------- flash attention v5: 8 waves, QBLK=128 ----------------
// K+V LDS dbuf (shared by 8 waves), swapped QK^T, shift-free softmax (bounded scores),
// l via ones-column MFMA.
__global__ __launch_bounds__(512, 4) void attn_kernel(const bf16* __restrict__ q,
                                                      const bf16* __restrict__ k,
                                                      const bf16* __restrict__ vt,
                                                      bf16* __restrict__ o) {
  int bid = blockIdx.x;  // 1024 blocks
  int virt = (bid & 7) * 128 + (bid >> 3);
  const int bh = virt >> 3;     // (b*16+h)
  const int qt = virt & 7;      // q-tile of 128
  const int b = bh >> 4, h = bh & 15;
  const int t = threadIdx.x, lane = t & 63, w = t >> 6;
  const int r16 = lane & 15, hi = lane >> 4;
  const int swp = r16 & 7;

  __shared__ bf16 lK[2][4096];
  __shared__ bf16 lV[2][4096];
  __shared__ bf16 lP[8][1024];
  bf16* myp = lP[w];

  const bf16* kp = k + (size_t)bh * 65536;
  const bf16* vp = vt + (size_t)bh * 65536;  // (d, s) layout

  const bf16* qp = q + ((size_t)bh * 1024 + qt * 128 + w * 16) * 64;
  bf16x8 aq0 = *(const bf16x8*)&qp[r16 * 64 + hi * 8];
  bf16x8 aq1 = *(const bf16x8*)&qp[r16 * 64 + 32 + hi * 8];

  bf16x8 ones;
#pragma unroll
  for (int i = 0; i < 8; ++i) ones[i] = (bf16)1.0f;

  // staging: 512 threads cover a full 64x64 tile in one pass (1 load K, 1 load V)
  const int srow0 = t >> 3, sc0 = t & 7;
  const int se = ((sc0 ^ (srow0 & 7)) << 3);

  f32x4 oacc[4] = {};
  f32x4 lacc = {};

  // prologue: stage K+V tile 0 (inverse-swizzled global source, linear LDS dest)
  gload_lds16(kp + (size_t)srow0 * 64 + se, &lK[0][t * 8]);
  gload_lds16(vp + (size_t)srow0 * 1024 + se, &lV[0][t * 8]);
  __syncthreads();

  int cur = 0;
  for (int kt = 0; kt < 16; ++kt) {
    if (kt < 15) {
      gload_lds16(kp + (kt + 1) * 4096 + (size_t)srow0 * 64 + se, &lK[cur ^ 1][t * 8]);
      gload_lds16(vp + (kt + 1) * 64 + (size_t)srow0 * 1024 + se, &lV[cur ^ 1][t * 8]);
    }
    // ---- swapped QK^T: sT[c][r] = S[q=r16][k = c*16 + hi*4 + r] (log2-scaled) ----
    f32x4 sT[4] = {};
    __builtin_amdgcn_s_setprio(1);
#pragma unroll
    for (int c = 0; c < 4; ++c) {
      int row = c * 16 + r16, sw = row & 7;
      bf16x8 bk0 = *(const bf16x8*)&lK[cur][row * 64 + ((hi ^ sw) << 3)];
      bf16x8 bk1 = *(const bf16x8*)&lK[cur][row * 64 + (((hi + 4) ^ sw) << 3)];
      sT[c] = MFMA16(bk0, aq0, sT[c]);
      sT[c] = MFMA16(bk1, aq1, sT[c]);
    }
    __builtin_amdgcn_s_setprio(0);
    // ---- shift-free softmax: p = exp2(sT)  (bounded scores, no max/rescale) ----
    bf16x4 pb[4];
#pragma unroll
    for (int c = 0; c < 4; ++c) {
#pragma unroll
      for (int r = 0; r < 4; ++r) pb[c][r] = (bf16)exp2f(sT[c][r]);
    }
    // P[q=r16][k=c*16+hi*4 .. +3] as one b64 store, same XOR swizzle as reads
#pragma unroll
    for (int c = 0; c < 4; ++c) {
      int eoff = r16 * 64 + (((c * 32 + hi * 8) ^ (swp << 4)) >> 1);
      *(bf16x4*)&myp[eoff] = pb[c];
    }
    // ---- PV: P (swizzled LDS) x V^T (swizzled LDS); ones-column gives row sums ----
    {
      bf16x8 pa0 = *(const bf16x8*)&myp[r16 * 64 + ((hi ^ swp) << 3)];
      bf16x8 pa1 = *(const bf16x8*)&myp[r16 * 64 + (((hi + 4) ^ swp) << 3)];
      __builtin_amdgcn_s_setprio(1);
#pragma unroll
      for (int c = 0; c < 4; ++c) {
        int row = c * 16 + r16, sw = row & 7;
        bf16x8 bv0 = *(const bf16x8*)&lV[cur][row * 64 + ((hi ^ sw) << 3)];
        bf16x8 bv1 = *(const bf16x8*)&lV[cur][row * 64 + (((hi + 4) ^ sw) << 3)];
        oacc[c] = MFMA16(pa0, bv0, oacc[c]);
        oacc[c] = MFMA16(pa1, bv1, oacc[c]);
      }
      lacc = MFMA16(pa0, ones, lacc);
      lacc = MFMA16(pa1, ones, lacc);
      __builtin_amdgcn_s_setprio(0);
    }
    __syncthreads();
    cur ^= 1;
  }
  // epilogue: lacc rows are q = hi*4 + r, matching oacc — no shuffles needed
  f32x4 inv;
#pragma unroll
  for (int r = 0; r < 4; ++r) inv[r] = 1.f / lacc[r];
#pragma unroll
  for (int c = 0; c < 4; ++c) {
#pragma unroll
    for (int r = 0; r < 4; ++r) {
      int srow = qt * 128 + w * 16 + hi * 4 + r;
      o[((size_t)b * 1024 + srow) * 1024 + h * 64 + c * 16 + r16] =
          (bf16)(oacc[c][r] * inv[r]);
    }
  }
}

extern "C" void kernel_launch(void* const* d_in, const int* in_sizes, int n_in,
                              void* d_out, int out_size, void* d_ws, size_t ws_size,
                              hipStream_t stream) {
  const float* x      = (const float*)d_in[0];  // (8,32,32,1024)
  const float* pos    = (const float*)d_in[1];  // (8,32,32,2)
  const float* cond   = (const float*)d_in[2];  // (8,768)
  const float* norm_w = (const float*)d_in[3];  // (1024,768)
  const float* qkv_w  = (const float*)d_in[4];  // (3072,1024)
  const float* out_w  = (const float*)d_in[5];  // (1024,1024)
  const float* scale  = (const float*)d_in[6];  // (16,)
  float* out = (float*)d_out;

  char* ws = (char*)d_ws;
  bf16* xn        = (bf16*)(ws + 0);           // 16.8 MB (reused as o_attn)
  bf16* qkv_w_bf  = (bf16*)(ws + 16777216);    // 6.3 MB
  bf16* out_w_bf  = (bf16*)(ws + 23068672);    // 2.1 MB
  float* nsp1     = (float*)(ws + 25165824);   // 32 KB
  bf16* qraw      = (bf16*)(ws + 25198592);    // 16.8 MB
  bf16* kraw      = (bf16*)(ws + 41975808);    // 16.8 MB
  bf16* vt        = (bf16*)(ws + 58753024);    // 16.8 MB
  bf16* o_attn    = xn;

  f2bf_kernel<<<3072, 256, 0, stream>>>(qkv_w, qkv_w_bf, 786432);
  f2bf_kernel<<<1024, 256, 0, stream>>>(out_w, out_w_bf, 262144);
  ns_kernel<<<32, 256, 0, stream>>>(cond, norm_w, nsp1);
  rmsnorm_kernel<<<2048, 256, 0, stream>>>(x, nsp1, xn);
  gemm256b<0><<<768, 512, 0, stream>>>(xn, qkv_w_bf, 24, qraw, kraw, vt, nullptr, nullptr,
                                       pos, scale);
  attn_kernel<<<1024, 512, 0, stream>>>(qraw, kraw, vt, o_attn);
  gemm256b<1><<<256, 512, 0, stream>>>(o_attn, out_w_bf, 8, nullptr, nullptr, nullptr, out, x,
                                       nullptr, nullptr);
}